// Round 20
// baseline (27.279 us; speedup 1.0000x reference)
//
#include <hip/hip_runtime.h>
#include <math.h>

#define NF    64      // filters
#define KT    402     // taps: arange(-201, 201)
#define KP    416     // padded taps = 13 * 32
#define NSTEP 13      // K-steps of 32
#define NS1   7       // steps in first s-half (0..6)
#define NS2   6       // steps in second s-half (7..12)
#define LIN   16000
#define LOUT  15599   // LIN - KT + 1
#define NB    16
#define NT    256     // output positions per block
#define SPAN  672     // NT + KP data span per block
#define NCHUNK 84     // SPAN / 8 staging chunks
#define SROW  680     // A copy-row stride (elems)
#define CPAD  260     // C-tile row stride (dwords); 260 mod 32 = 4
#define TT    256     // 4 waves per block

typedef __attribute__((ext_vector_type(8))) _Float16 half8;  // MFMA f16 operand
typedef __attribute__((ext_vector_type(4))) float f32x4;     // MFMA acc
typedef __attribute__((ext_vector_type(4), aligned(4))) float f32x4u;

// Raw barrier that does NOT drain vmcnt: in-flight global stores / gll16
// stay outstanding across it (lgkmcnt(0) orders the LDS ops; "memory"
// clobber + sched_barrier pin compiler ordering -- guide rule #18).
#define LBAR() do {                                              \
    asm volatile("s_waitcnt lgkmcnt(0)" ::: "memory");           \
    __builtin_amdgcn_s_barrier();                                \
    __builtin_amdgcn_sched_barrier(0);                           \
} while (0)

// fp32 planes [plane][k][f] for the complex fallback path.
__device__ float g_filt[2 * KT * NF];
// fp16 B plane, MFMA fragment order: [group][s][lane][j] =
// fp16(coef(filter = 16*group + (lane&15), tap = 8*(lane>>4) + 32*s + j)).
// Each [group][s] slice is 1 KB contiguous -> one gll16 per wave.
__device__ __align__(16) short g_cbh[4][NSTEP][64][8];

__device__ __forceinline__ short f2h(float v) {
    _Float16 h = (_Float16)v;               // v_cvt_f16_f32 (RNE)
    union { _Float16 h; short s; } u; u.h = h;
    return u.s;
}
// Async global->LDS 16B: per-lane global src, wave-uniform LDS base (+lane*16).
__device__ __forceinline__ void gll16(const void* g, void* l) {
    __builtin_amdgcn_global_load_lds(
        (const __attribute__((address_space(1))) void*)g,
        (__attribute__((address_space(3))) void*)l, 16, 0, 0);
}

__global__ void gabor_build_filters(const float* __restrict__ cf,
                                    const float* __restrict__ bw) {
    int idx = blockIdx.x * blockDim.x + threadIdx.x;    // f*KP + k
    if (idx >= NF * KP) return;
    int f = idx / KP;
    int k = idx - f * KP;
    float cre = 0.0f;
    if (k < KT) {
        float t = (float)(k - 201);
        float b = bw[f];
        float env = expf(-(t * t) / (2.0f * b * b)) / (sqrtf(2.0f * (float)M_PI) * b);
        float s, c;
        sincosf(cf[f] * t, &s, &c);
        cre = env * c;
        g_filt[k * NF + f]           = cre;      // re plane (fallback)
        g_filt[KT * NF + k * NF + f] = env * s;  // im plane (fallback)
    }
    int g = f >> 4;
    int s = k >> 5;
    int q = (k >> 3) & 3;
    int j = k & 7;
    int l = (f & 15) | (q << 4);
    g_cbh[g][s][l][j] = f2h(cre);
}

// MFMA implicit GEMM, real part only, fp16 1-term (R18: error floor is the
// shared fp32 filter-build ULP noise; absmax invariant across schemes).
// R20 structure: TWO GROUP-PASSES (filters 0-31 then 32-63, acc[4][2]) so
// pass-0's epilogue stores drain UNDER pass-1's K-loop. Enablers:
//  (1) pass-1's B gll16s are issued BEFORE pass-0's epilogue;
//  (2) epilogue barriers are raw s_barrier + lgkmcnt(0) ONLY -- no vmcnt
//      drain, so the 8 stores/thread stay in flight (R19 post-mortem:
//      __syncthreads' vmcnt(0) drained store bursts -> zero overlap,
//      kernel ran at sum-of-phases = 27.5 us);
//  (3) counted vmcnt(8) before pass-1's K: vmcnt retires in issue order,
//      8 = stores issued after the gll16s -> B landed, stores still flying.
// B staged per pass in two s-halves (7+6) into a [7][2] region; C-tile is
// 8 rows (separate region, no union) -> LDS 33.5 KB -> 4 blocks/CU.
__global__ __launch_bounds__(TT, 4) void gabor_conv_mfma(const float* __restrict__ x,
                                                         float* __restrict__ out,
                                                         long out_elems) {
    __shared__ __align__(16) struct {
        short h[8][SROW];              // 10,880 B  (fp16 x, 8 shifted copies)
        short bh[NS1][2][64][8];       // 14,336 B  (B: one group-pair s-half)
        float c[8][CPAD];              //  8,320 B  (C transpose tile, 8 rows)
    } sm;

    const int tile = blockIdx.x;
    const int b    = blockIdx.y;
    const int n0   = tile * NT;
    const int tid  = threadIdx.x;
    const int wid  = tid >> 6;      // 0..3
    const int lane = tid & 63;

    // Stage B(groups 0,1; s=0..6): 14 slices of 1 KB round-robin over waves.
    for (int i = wid; i < 2 * NS1; i += 4) {
        const int gg = i & 1, ss = i >> 1;
        gll16(&g_cbh[gg][ss][lane][0], &sm.bh[ss][gg][0][0]);
    }

    // ---- Vectorized A staging: thread j < 84 owns x elements [8j, 8j+16),
    // builds all 8 shifted fp16 windows in registers, writes 8 ds_write_b128.
    if (tid < NCHUNK) {
        const int j  = tid;
        const int e0 = 8 * j;
        const float* __restrict__ src = x + (size_t)b * LIN + n0 + e0;

        float xv[16];
        if (n0 + e0 + 16 <= LIN) {
#pragma unroll
            for (int q = 0; q < 4; ++q) {
                float4 v = *reinterpret_cast<const float4*>(src + 4 * q);
                xv[4 * q + 0] = v.x; xv[4 * q + 1] = v.y;
                xv[4 * q + 2] = v.z; xv[4 * q + 3] = v.w;
            }
        } else {
#pragma unroll
            for (int i = 0; i < 16; ++i) {
                int gi = n0 + e0 + i;
                xv[i] = (gi < LIN) ? src[i] : 0.0f;
            }
        }

        unsigned hd[8];          // packed fp16 pairs (low16 = even elem)
#pragma unroll
        for (int i = 0; i < 8; ++i) {
            unsigned h0 = (unsigned short)f2h(xv[2 * i]);
            unsigned h1 = (unsigned short)f2h(xv[2 * i + 1]);
            hd[i] = h0 | (h1 << 16);
        }

#pragma unroll
        for (int c = 0; c < 8; ++c) {
            unsigned wh[4];
            if ((c & 1) == 0) {
#pragma unroll
                for (int i = 0; i < 4; ++i) wh[i] = hd[c / 2 + i];
            } else {
#pragma unroll
                for (int i = 0; i < 4; ++i) {
                    int k2 = (c - 1) / 2 + i;
                    wh[i] = (hd[k2] >> 16) | (hd[k2 + 1] << 16);   // v_alignbit
                }
            }
            uint4 vh = {wh[0], wh[1], wh[2], wh[3]};
            *reinterpret_cast<uint4*>(&sm.h[c][e0]) = vh;
        }
    }
    __syncthreads();    // drains A ds_writes + B(g01,s0-6) gll16

    const int c8      = lane & 7;
    const int abase   = 8 * ((lane >> 3) & 1) + 8 * (lane >> 4);
    const int subbase = wid * 4;    // this wave's first position-subtile
    const short* ah_base = &sm.h[c8][abase + 16 * subbase];

#pragma unroll
    for (int P = 0; P < 2; ++P) {           // group-pass: filters 32P..32P+31
        f32x4 acc[4][2];
#pragma unroll
        for (int n = 0; n < 4; ++n)
#pragma unroll
            for (int g = 0; g < 2; ++g) {
                f32x4 z = {0.0f, 0.0f, 0.0f, 0.0f};
                acc[n][g] = z;
            }

        // K s-half 1 (s = 0..6). B validity: P=0 prologue sync; P=1 vmcnt(8).
#pragma unroll
        for (int ss = 0; ss < NS1; ++ss) {
            half8 b0 = *reinterpret_cast<const half8*>(&sm.bh[ss][0][lane][0]);
            half8 b1 = *reinterpret_cast<const half8*>(&sm.bh[ss][1][lane][0]);
#pragma unroll
            for (int n = 0; n < 4; ++n) {
                half8 ah = *reinterpret_cast<const half8*>(ah_base + 16 * n + 32 * ss);
                acc[n][0] = __builtin_amdgcn_mfma_f32_16x16x32_f16(ah, b0, acc[n][0], 0, 0, 0);
                acc[n][1] = __builtin_amdgcn_mfma_f32_16x16x32_f16(ah, b1, acc[n][1], 0, 0, 0);
            }
        }
        LBAR();     // all waves done reading B s-half 1

        // Stage B(this pass's groups; s = 7..12): 12 slices.
        for (int i = wid; i < 2 * NS2; i += 4) {
            const int gg = i & 1, ss = i >> 1;
            gll16(&g_cbh[2 * P + gg][NS1 + ss][lane][0], &sm.bh[ss][gg][0][0]);
        }
        __syncthreads();    // drain gll16 (P0: no stores yet; P1: old stores long gone)

        // K s-half 2 (s = 7..12).
#pragma unroll
        for (int ss = 0; ss < NS2; ++ss) {
            const int s = NS1 + ss;
            half8 b0 = *reinterpret_cast<const half8*>(&sm.bh[ss][0][lane][0]);
            half8 b1 = *reinterpret_cast<const half8*>(&sm.bh[ss][1][lane][0]);
#pragma unroll
            for (int n = 0; n < 4; ++n) {
                half8 ah = *reinterpret_cast<const half8*>(ah_base + 16 * n + 32 * s);
                acc[n][0] = __builtin_amdgcn_mfma_f32_16x16x32_f16(ah, b0, acc[n][0], 0, 0, 0);
                acc[n][1] = __builtin_amdgcn_mfma_f32_16x16x32_f16(ah, b1, acc[n][1], 0, 0, 0);
            }
        }
        LBAR();     // done reading B region (and A for this pass)

        // Issue NEXT pass's B(s=0..6) gll16 BEFORE this pass's epilogue so
        // the stage lands while we scatter/write (stores never drained here).
        if (P == 0) {
            for (int i = wid; i < 2 * NS1; i += 4) {
                const int gg = i & 1, ss = i >> 1;
                gll16(&g_cbh[2 + gg][ss][lane][0], &sm.bh[ss][gg][0][0]);
            }
        }

        // ---- Epilogue for filters 32P..32P+31: 4 rounds of 8 rows via the
        // 8-row C transpose tile. Raw LBAR only -- stores stay in flight.
#pragma unroll
        for (int rnd = 0; rnd < 4; ++rnd) {
            const int gg = rnd >> 1;        // group within pass
            const int rh = rnd & 1;         // row-half within group
            // Scatter: lanes whose filter-row (lane&15) is in [8rh, 8rh+8).
            if (((lane >> 3) & 1) == rh) {
#pragma unroll
                for (int n = 0; n < 4; ++n) {
                    const int colbase = 16 * (subbase + n) + 4 * (lane >> 4);
                    *reinterpret_cast<f32x4*>(&sm.c[lane & 7][colbase]) = acc[n][gg];
                }
            }
            LBAR();
            // Write 8 rows: wave covers rows 2w, 2w+1; 2 col-chunks of 128.
            const int rloc = 2 * wid + (lane >> 5);
            const int f    = 32 * P + 16 * gg + 8 * rh + rloc;
#pragma unroll
            for (int cc = 0; cc < 2; ++cc) {
                const int col = 4 * (lane & 31) + 128 * cc;
                const int np  = n0 + col;
                const size_t o = (size_t)(b * NF + f) * LOUT + np;
                f32x4 v = *reinterpret_cast<const f32x4*>(&sm.c[rloc][col]);
                if (np + 3 < LOUT && (long)(o + 3) < out_elems) {
                    *reinterpret_cast<f32x4u*>(out + o) = v;
                } else {
#pragma unroll
                    for (int r = 0; r < 4; ++r)
                        if (np + r < LOUT && (long)(o + r) < out_elems)
                            out[o + r] = v[r];
                }
            }
            LBAR();
        }

        if (P == 0) {
            // Counted wait: >=8 stores were issued AFTER the 2..4 gll16s of
            // the next pass; vmcnt retires in order, so <=8 outstanding
            // implies the gll16s landed. Stores may still be in flight.
            asm volatile("s_waitcnt vmcnt(8)" ::: "memory");
            __builtin_amdgcn_s_barrier();
            __builtin_amdgcn_sched_barrier(0);
        }
    }
}

// Complex fallback (folded fp32) in case d_out is interleaved complex.
__global__ __launch_bounds__(256) void gabor_conv_cplx(const float* __restrict__ x,
                                                       float* __restrict__ out,
                                                       long out_elems) {
    __shared__ float sx[256 + KT];
    const int tile = blockIdx.x, g = blockIdx.y, b = blockIdx.z;
    const int t0 = tile * 256, tid = threadIdx.x;
    const float* __restrict__ xb = x + (size_t)b * LIN;
    for (int i = tid; i < 256 + KT - 1; i += 256) {
        int idx = t0 + i;
        sx[i] = (idx < LIN) ? xb[idx] : 0.0f;
    }
    __syncthreads();
    const float* fre = g_filt + g * 16;
    const float* fim = g_filt + KT * NF + g * 16;
    float accre[16], accim[16];
    {
        float x0 = sx[tid], xm = sx[tid + 201];
        const float* c0 = fre;
        const float* cm = fre + 201 * NF;
#pragma unroll
        for (int j = 0; j < 16; ++j) accre[j] = __builtin_fmaf(xm, cm[j], x0 * c0[j]);
#pragma unroll
        for (int j = 0; j < 16; ++j) accim[j] = x0 * fim[j];
    }
#pragma unroll 2
    for (int p = 1; p <= 200; ++p) {
        float x1 = sx[tid + p], x2 = sx[tid + 402 - p];
        float xs = x1 + x2, xd = x1 - x2;
        const float* cr = fre + p * NF;
        const float* ci = fim + p * NF;
#pragma unroll
        for (int j = 0; j < 16; ++j) accre[j] = __builtin_fmaf(xs, cr[j], accre[j]);
#pragma unroll
        for (int j = 0; j < 16; ++j) accim[j] = __builtin_fmaf(xd, ci[j], accim[j]);
    }
    const int t = t0 + tid;
    if (t < LOUT) {
#pragma unroll
        for (int j = 0; j < 16; ++j) {
            size_t o = ((size_t)(b * NF + g * 16 + j) * LOUT + t) * 2;
            if ((long)(o + 1) < out_elems) {
                float2 v; v.x = accre[j]; v.y = accim[j];
                *reinterpret_cast<float2*>(out + o) = v;
            }
        }
    }
}

extern "C" void kernel_launch(void* const* d_in, const int* in_sizes, int n_in,
                              void* d_out, int out_size, void* d_ws, size_t ws_size,
                              hipStream_t stream) {
    const float* x  = (const float*)d_in[0];
    const float* cf = (const float*)d_in[1];
    const float* bw = (const float*)d_in[2];
    float* out = (float*)d_out;
    (void)d_ws; (void)ws_size;

    {
        int n = NF * KP;
        gabor_build_filters<<<(n + 255) / 256, 256, 0, stream>>>(cf, bw);
    }

    const long n_complex = (long)NB * NF * LOUT;
    const bool cplx = ((long)out_size >= 2 * n_complex);

    if (cplx) {
        dim3 grid((LOUT + 255) / 256, NF / 16, NB);
        gabor_conv_cplx<<<grid, 256, 0, stream>>>(x, out, (long)out_size);
    } else {
        dim3 grid((LOUT + NT - 1) / NT, NB);   // (61, 16)
        gabor_conv_mfma<<<grid, TT, 0, stream>>>(x, out, (long)out_size);
    }
}

// Round 21
// 26.181 us; speedup vs baseline: 1.0419x; 1.0419x over previous
//
#include <hip/hip_runtime.h>
#include <math.h>

#define NF    64      // filters
#define KT    402     // taps: arange(-201, 201)
#define KP    416     // padded taps = 13 * 32
#define NSTEP 13      // K-steps of 32
#define NS1   7       // steps in first half (s = 0..6)
#define NS2   6       // steps in second half (s = 7..12)
#define LIN   16000
#define LOUT  15599   // LIN - KT + 1
#define NB    16
#define NT    256     // output positions per block
#define SPAN  672     // NT + KP data span per block
#define NCHUNK 84     // SPAN / 8 staging chunks
#define SROW  680     // A copy-row stride (elems)
#define CPAD  260     // C-tile row stride (dwords); 260 mod 32 = 4
#define TT    256     // 4 waves per block

typedef __attribute__((ext_vector_type(8))) _Float16 half8;  // MFMA f16 operand
typedef __attribute__((ext_vector_type(4))) float f32x4;     // MFMA acc
typedef __attribute__((ext_vector_type(4), aligned(4))) float f32x4u;

// LDS-only barrier: orders ds ops across the block WITHOUT draining vmcnt,
// so in-flight global stores keep draining under subsequent LDS work
// (R19's __syncthreads epilogue barriers each drained the store burst).
#define LBAR() do {                                              \
    asm volatile("s_waitcnt lgkmcnt(0)" ::: "memory");           \
    __builtin_amdgcn_s_barrier();                                \
    __builtin_amdgcn_sched_barrier(0);                           \
} while (0)

// fp32 planes [plane][k][f] for the complex fallback path.
__device__ float g_filt[2 * KT * NF];
// fp16 B plane, MFMA fragment order: [group][s][lane][j] =
// fp16(coef(filter = 16*group + (lane&15), tap = 8*(lane>>4) + 32*s + j)).
__device__ __align__(16) short g_cbh[4][NSTEP][64][8];

__device__ __forceinline__ short f2h(float v) {
    _Float16 h = (_Float16)v;               // v_cvt_f16_f32 (RNE)
    union { _Float16 h; short s; } u; u.h = h;
    return u.s;
}
// Async global->LDS 16B: per-lane global src, wave-uniform LDS base (+lane*16).
__device__ __forceinline__ void gll16(const void* g, void* l) {
    __builtin_amdgcn_global_load_lds(
        (const __attribute__((address_space(1))) void*)g,
        (__attribute__((address_space(3))) void*)l, 16, 0, 0);
}

__global__ void gabor_build_filters(const float* __restrict__ cf,
                                    const float* __restrict__ bw) {
    int idx = blockIdx.x * blockDim.x + threadIdx.x;    // f*KP + k
    if (idx >= NF * KP) return;
    int f = idx / KP;
    int k = idx - f * KP;
    float cre = 0.0f;
    if (k < KT) {
        float t = (float)(k - 201);
        float b = bw[f];
        float env = expf(-(t * t) / (2.0f * b * b)) / (sqrtf(2.0f * (float)M_PI) * b);
        float s, c;
        sincosf(cf[f] * t, &s, &c);
        cre = env * c;
        g_filt[k * NF + f]           = cre;      // re plane (fallback)
        g_filt[KT * NF + k * NF + f] = env * s;  // im plane (fallback)
    }
    int g = f >> 4;
    int s = k >> 5;
    int q = (k >> 3) & 3;
    int j = k & 7;
    int l = (f & 15) | (q << 4);
    g_cbh[g][s][l][j] = f2h(cre);
}

// MFMA implicit GEMM, real part only, fp16 1-term (out = fp16(x)*fp16(c);
// error floor is the shared fp32 filter-build ULP noise -- absmax invariant
// across 3 precision schemes, R18 evidence). R19 structure (best, 26.4 us):
// B staged in two s-halves (s=0..6 then 7..12 re-staged) -> LDS 38.6 KB ->
// 4 blocks/CU, all 976 blocks co-resident. R21 change: epilogue barriers are
// LDS-only (LBAR) so half-0's store burst drains under half-1's scatter and
// stream-out (R19's __syncthreads vmcnt(0)-drained each burst; R20 showed
// bigger restructures regress -- this is the bounded-risk overlap).
__global__ __launch_bounds__(TT, 4) void gabor_conv_mfma(const float* __restrict__ x,
                                                         float* __restrict__ out,
                                                         long out_elems) {
    __shared__ __align__(16) union {
        struct {
            short h[8][SROW];              // 10,880 B  (fp16 x, 8 shifted copies)
            short bh[NS1][4][64][8];       // 28,672 B  (one B s-half)
        } k;                               // 39,552 B
        float c[32][CPAD];                 // 33,280 B (half C-tile)
    } sm;

    const int tile = blockIdx.x;
    const int b    = blockIdx.y;
    const int n0   = tile * NT;
    const int tid  = threadIdx.x;
    const int wid  = tid >> 6;      // 0..3
    const int lane = tid & 63;

    // Stage B half 1: wave w covers group w, steps 0..6 (1 KB each).
#pragma unroll
    for (int s = 0; s < NS1; ++s)
        gll16(&g_cbh[wid][s][lane][0], &sm.k.bh[s][wid][0][0]);

    // ---- Vectorized A staging: thread j < 84 owns x elements [8j, 8j+16),
    // builds all 8 shifted fp16 windows in registers, writes 8 ds_write_b128.
    if (tid < NCHUNK) {
        const int j  = tid;
        const int e0 = 8 * j;
        const float* __restrict__ src = x + (size_t)b * LIN + n0 + e0;

        float xv[16];
        if (n0 + e0 + 16 <= LIN) {
#pragma unroll
            for (int q = 0; q < 4; ++q) {
                float4 v = *reinterpret_cast<const float4*>(src + 4 * q);
                xv[4 * q + 0] = v.x; xv[4 * q + 1] = v.y;
                xv[4 * q + 2] = v.z; xv[4 * q + 3] = v.w;
            }
        } else {
#pragma unroll
            for (int i = 0; i < 16; ++i) {
                int gi = n0 + e0 + i;
                xv[i] = (gi < LIN) ? src[i] : 0.0f;
            }
        }

        unsigned hd[8];          // packed fp16 pairs (low16 = even elem)
#pragma unroll
        for (int i = 0; i < 8; ++i) {
            unsigned h0 = (unsigned short)f2h(xv[2 * i]);
            unsigned h1 = (unsigned short)f2h(xv[2 * i + 1]);
            hd[i] = h0 | (h1 << 16);
        }

#pragma unroll
        for (int c = 0; c < 8; ++c) {
            unsigned wh[4];
            if ((c & 1) == 0) {
#pragma unroll
                for (int i = 0; i < 4; ++i) wh[i] = hd[c / 2 + i];
            } else {
#pragma unroll
                for (int i = 0; i < 4; ++i) {
                    int k2 = (c - 1) / 2 + i;
                    wh[i] = (hd[k2] >> 16) | (hd[k2 + 1] << 16);   // v_alignbit
                }
            }
            uint4 vh = {wh[0], wh[1], wh[2], wh[3]};
            *reinterpret_cast<uint4*>(&sm.k.h[c][e0]) = vh;
        }
    }
    __syncthreads();    // drains A ds_writes + B half-1 gll16 stages

    // ---- K-loop
    const int c8    = lane & 7;
    const int abase = 8 * ((lane >> 3) & 1) + 8 * (lane >> 4);
    const int subbase = wid * 4;    // this wave's first position-subtile
    const short* ah_base = &sm.k.h[c8][abase + 16 * subbase];

    f32x4 acc[4][4];                // [n][group], all-static indexing
#pragma unroll
    for (int n = 0; n < 4; ++n)
#pragma unroll
        for (int g = 0; g < 4; ++g) {
            f32x4 z = {0.0f, 0.0f, 0.0f, 0.0f};
            acc[n][g] = z;
        }

    // Half 1: s = 0..6, barrier-free.
#pragma unroll
    for (int s = 0; s < NS1; ++s) {
        half8 bh[4];
#pragma unroll
        for (int g = 0; g < 4; ++g)
            bh[g] = *reinterpret_cast<const half8*>(&sm.k.bh[s][g][lane][0]);
#pragma unroll
        for (int n = 0; n < 4; ++n) {
            half8 ah = *reinterpret_cast<const half8*>(ah_base + 16 * n + 32 * s);
#pragma unroll
            for (int g = 0; g < 4; ++g)
                acc[n][g] = __builtin_amdgcn_mfma_f32_16x16x32_f16(ah, bh[g], acc[n][g], 0, 0, 0);
        }
    }

    // Re-stage B half 2 (s = 7..12) into the same region.
    __syncthreads();    // all waves done reading half-1 B (no stores in flight)
#pragma unroll
    for (int s = 0; s < NS2; ++s)
        gll16(&g_cbh[wid][NS1 + s][lane][0], &sm.k.bh[s][wid][0][0]);
    __syncthreads();    // half-2 stages landed (vmcnt drained; still no stores)

    // Half 2: s = 7..12, barrier-free.
#pragma unroll
    for (int s2 = 0; s2 < NS2; ++s2) {
        const int s = NS1 + s2;
        half8 bh[4];
#pragma unroll
        for (int g = 0; g < 4; ++g)
            bh[g] = *reinterpret_cast<const half8*>(&sm.k.bh[s2][g][lane][0]);
#pragma unroll
        for (int n = 0; n < 4; ++n) {
            half8 ah = *reinterpret_cast<const half8*>(ah_base + 16 * n + 32 * s);
#pragma unroll
            for (int g = 0; g < 4; ++g)
                acc[n][g] = __builtin_amdgcn_mfma_f32_16x16x32_f16(ah, bh[g], acc[n][g], 0, 0, 0);
        }
    }

    // ---- Epilogue: two half-tile LDS-transpose passes -> coalesced stores.
    // ALL barriers here are LDS-only: scatter/stream hazards are LDS-ordered
    // (ds ops complete before each wave's lgkmcnt(0)); global stores read
    // their source VGPRs at issue, so clobbering sm.c afterwards is safe --
    // half-0's stores drain under half-1's scatter + stream.
    LBAR();             // K-loop ds_reads done before scatter clobbers union

#pragma unroll
    for (int half = 0; half < 2; ++half) {
#pragma unroll
        for (int n = 0; n < 4; ++n) {
            const int colbase = 16 * (subbase + n) + 4 * (lane >> 4);
#pragma unroll
            for (int gg = 0; gg < 2; ++gg) {
                const int row = 16 * gg + (lane & 15);   // row within half-tile
                *reinterpret_cast<f32x4*>(&sm.c[row][colbase]) = acc[n][2 * half + gg];
            }
        }
        LBAR();         // scatter ds_writes visible before stream ds_reads

        // Stream out: one full 256-pos row per wave-instruction (1024 B).
#pragma unroll
        for (int rr = 0; rr < 8; ++rr) {
            const int rloc = 8 * wid + rr;               // 0..31
            const int f    = 32 * half + rloc;           // filter index
            const int np   = n0 + 4 * lane;
            const size_t o = (size_t)(b * NF + f) * LOUT + np;
            f32x4 v = *reinterpret_cast<const f32x4*>(&sm.c[rloc][4 * lane]);
            if (np + 3 < LOUT && (long)(o + 3) < out_elems) {
                *reinterpret_cast<f32x4u*>(out + o) = v;
            } else {
#pragma unroll
                for (int r = 0; r < 4; ++r)
                    if (np + r < LOUT && (long)(o + r) < out_elems)
                        out[o + r] = v[r];
            }
        }
        if (half == 0) LBAR();   // stream ds_reads done; stores stay in flight
    }
}

// Complex fallback (folded fp32) in case d_out is interleaved complex.
__global__ __launch_bounds__(256) void gabor_conv_cplx(const float* __restrict__ x,
                                                       float* __restrict__ out,
                                                       long out_elems) {
    __shared__ float sx[256 + KT];
    const int tile = blockIdx.x, g = blockIdx.y, b = blockIdx.z;
    const int t0 = tile * 256, tid = threadIdx.x;
    const float* __restrict__ xb = x + (size_t)b * LIN;
    for (int i = tid; i < 256 + KT - 1; i += 256) {
        int idx = t0 + i;
        sx[i] = (idx < LIN) ? xb[idx] : 0.0f;
    }
    __syncthreads();
    const float* fre = g_filt + g * 16;
    const float* fim = g_filt + KT * NF + g * 16;
    float accre[16], accim[16];
    {
        float x0 = sx[tid], xm = sx[tid + 201];
        const float* c0 = fre;
        const float* cm = fre + 201 * NF;
#pragma unroll
        for (int j = 0; j < 16; ++j) accre[j] = __builtin_fmaf(xm, cm[j], x0 * c0[j]);
#pragma unroll
        for (int j = 0; j < 16; ++j) accim[j] = x0 * fim[j];
    }
#pragma unroll 2
    for (int p = 1; p <= 200; ++p) {
        float x1 = sx[tid + p], x2 = sx[tid + 402 - p];
        float xs = x1 + x2, xd = x1 - x2;
        const float* cr = fre + p * NF;
        const float* ci = fim + p * NF;
#pragma unroll
        for (int j = 0; j < 16; ++j) accre[j] = __builtin_fmaf(xs, cr[j], accre[j]);
#pragma unroll
        for (int j = 0; j < 16; ++j) accim[j] = __builtin_fmaf(xd, ci[j], accim[j]);
    }
    const int t = t0 + tid;
    if (t < LOUT) {
#pragma unroll
        for (int j = 0; j < 16; ++j) {
            size_t o = ((size_t)(b * NF + g * 16 + j) * LOUT + t) * 2;
            if ((long)(o + 1) < out_elems) {
                float2 v; v.x = accre[j]; v.y = accim[j];
                *reinterpret_cast<float2*>(out + o) = v;
            }
        }
    }
}

extern "C" void kernel_launch(void* const* d_in, const int* in_sizes, int n_in,
                              void* d_out, int out_size, void* d_ws, size_t ws_size,
                              hipStream_t stream) {
    const float* x  = (const float*)d_in[0];
    const float* cf = (const float*)d_in[1];
    const float* bw = (const float*)d_in[2];
    float* out = (float*)d_out;
    (void)d_ws; (void)ws_size;

    {
        int n = NF * KP;
        gabor_build_filters<<<(n + 255) / 256, 256, 0, stream>>>(cf, bw);
    }

    const long n_complex = (long)NB * NF * LOUT;
    const bool cplx = ((long)out_size >= 2 * n_complex);

    if (cplx) {
        dim3 grid((LOUT + 255) / 256, NF / 16, NB);
        gabor_conv_cplx<<<grid, 256, 0, stream>>>(x, out, (long)out_size);
    } else {
        dim3 grid((LOUT + NT - 1) / NT, NB);   // (61, 16)
        gabor_conv_mfma<<<grid, TT, 0, stream>>>(x, out, (long)out_size);
    }
}